// Round 1
// baseline (87.518 us; speedup 1.0000x reference)
//
#include <hip/hip_runtime.h>

// Forward-fill per row: out[b,n] = A[b, m] for the largest m <= n with
// W[b,m]==0 (index 0 always counts). One 64-lane wave per row; 256-elem
// chunks (float4/int4 per lane); (defined,value) shuffle scan across lanes;
// scalar carry across chunks.

constexpr int S_CONST = 8192;
constexpr int VEC = 4;                 // elements per lane per chunk
constexpr int CHUNK = 64 * VEC;        // 256 elements
// chunks per row computed from S at runtime (S fixed here)

__global__ __launch_bounds__(256) void ffill_kernel(const float* __restrict__ A,
                                                    const int* __restrict__ W,
                                                    float* __restrict__ O,
                                                    int B) {
    const int wave = (blockIdx.x * blockDim.x + threadIdx.x) >> 6;
    const int lane = threadIdx.x & 63;
    if (wave >= B) return;

    const float4* __restrict__ Arow =
        reinterpret_cast<const float4*>(A + (size_t)wave * S_CONST);
    const int4* __restrict__ Wrow =
        reinterpret_cast<const int4*>(W + (size_t)wave * S_CONST);
    float4* __restrict__ Orow =
        reinterpret_cast<float4*>(O + (size_t)wave * S_CONST);

    const int nchunk = S_CONST / CHUNK;   // 32

    float carry = 0.0f;  // element 0 is always "dry", so init value never leaks

    for (int c = 0; c < nchunk; ++c) {
        const int vi = c * 64 + lane;     // float4 index within row
        const float4 a = Arow[vi];
        const int4 w = Wrow[vi];

        const bool first_elem = (c == 0) & (lane == 0);  // global idx 0

        // Per-lane summary: last dry value among this lane's 4 elements.
        float val = 0.0f;
        int def = 0;
        if ((w.x == 0) || first_elem) { val = a.x; def = 1; }
        if (w.y == 0)                 { val = a.y; def = 1; }
        if (w.z == 0)                 { val = a.z; def = 1; }
        if (w.w == 0)                 { val = a.w; def = 1; }

        // Inclusive scan across 64 lanes: last defined (val) in lanes [0..i].
        // op(a,b) = b.def ? b : a  — Hillis-Steele; out-of-range shfl_up
        // returns own value, and (!sd -> take own) is a no-op, so no guard
        // needed.
        float sv = val;
        int sd = def;
        #pragma unroll
        for (int d = 1; d < 64; d <<= 1) {
            float ov = __shfl_up(sv, d);
            int od = __shfl_up(sd, d);
            if (!sd) { sv = ov; sd = od; }
        }

        // Exclusive prefix for this lane (lanes [0..i-1]).
        float pv = __shfl_up(sv, 1);
        int pd = __shfl_up(sd, 1);
        if (lane == 0) pd = 0;
        float lane_carry = pd ? pv : carry;

        // Re-run the in-lane fill seeded with lane_carry.
        float run = lane_carry;
        float4 o;
        if ((w.x == 0) || first_elem) run = a.x;
        o.x = run;
        if (w.y == 0) run = a.y;
        o.y = run;
        if (w.z == 0) run = a.z;
        o.z = run;
        if (w.w == 0) run = a.w;
        o.w = run;
        Orow[vi] = o;

        // Update the cross-chunk carry from lane 63's inclusive result.
        float lv = __shfl(sv, 63);
        int ld = __shfl(sd, 63);
        carry = ld ? lv : carry;
    }
}

extern "C" void kernel_launch(void* const* d_in, const int* in_sizes, int n_in,
                              void* d_out, int out_size, void* d_ws, size_t ws_size,
                              hipStream_t stream) {
    const float* A = (const float*)d_in[0];
    const int* W = (const int*)d_in[1];
    float* O = (float*)d_out;

    const int B = in_sizes[0] / S_CONST;

    const int threads = 256;                       // 4 waves per block
    const int blocks = (B * 64 + threads - 1) / threads;
    hipLaunchKernelGGL(ffill_kernel, dim3(blocks), dim3(threads), 0, stream,
                       A, W, O, B);
}

// Round 3
// 63.270 us; speedup vs baseline: 1.3832x; 1.3832x over previous
//
#include <hip/hip_runtime.h>

// Forward-fill per row via ballot + single-bpermute "last defined" scan.
// One 64-lane wave per row. 512-element chunks: each lane holds two
// contiguous 4-element groups (f32x4 at base and base+64), so global loads
// stay perfectly coalesced. Cross-lane work per 512 elems: 2 ballots + 4
// bpermutes (vs 32 shuffles for a Hillis-Steele scan).

typedef float f32x4 __attribute__((ext_vector_type(4)));
typedef int i32x4 __attribute__((ext_vector_type(4)));

constexpr int S_CONST = 8192;
constexpr int CHUNK = 512;
constexpr int NCHUNK = S_CONST / CHUNK;  // 16

__global__ __launch_bounds__(256) void ffill_kernel(const float* __restrict__ A,
                                                    const int* __restrict__ W,
                                                    float* __restrict__ O,
                                                    int B) {
    const int wave = (blockIdx.x * blockDim.x + threadIdx.x) >> 6;
    const int lane = threadIdx.x & 63;
    if (wave >= B) return;

    const f32x4* __restrict__ Arow =
        reinterpret_cast<const f32x4*>(A + (size_t)wave * S_CONST);
    const i32x4* __restrict__ Wrow =
        reinterpret_cast<const i32x4*>(W + (size_t)wave * S_CONST);
    f32x4* __restrict__ Orow =
        reinterpret_cast<f32x4*>(O + (size_t)wave * S_CONST);

    float carry = 0.0f;  // elem 0 is always defined, so never leaks
    const unsigned long long below = ((unsigned long long)1 << lane) - 1ull;

    #pragma unroll 4
    for (int c = 0; c < NCHUNK; ++c) {
        const int base = c * 128 + lane;  // f32x4 index within row
        const f32x4 a1 = Arow[base];
        const f32x4 a2 = Arow[base + 64];
        const i32x4 w1 = Wrow[base];
        const i32x4 w2 = Wrow[base + 64];

        const bool first = (c == 0) & (lane == 0);  // global element 0

        // Per-group summary: last dry value among this lane's 4 elements.
        float v1 = 0.f; int d1 = 0;
        if ((w1.x == 0) | first) { v1 = a1.x; d1 = 1; }
        if (w1.y == 0)           { v1 = a1.y; d1 = 1; }
        if (w1.z == 0)           { v1 = a1.z; d1 = 1; }
        if (w1.w == 0)           { v1 = a1.w; d1 = 1; }
        float v2 = 0.f; int d2 = 0;
        if (w2.x == 0) { v2 = a2.x; d2 = 1; }
        if (w2.y == 0) { v2 = a2.y; d2 = 1; }
        if (w2.z == 0) { v2 = a2.z; d2 = 1; }
        if (w2.w == 0) { v2 = a2.w; d2 = 1; }

        const unsigned long long m1 = __ballot(d1);
        const unsigned long long m2 = __ballot(d2);
        const unsigned long long p1 = m1 & below;
        const unsigned long long p2 = m2 & below;

        // Highest set bit <= position; |1 makes clz garbage-safe (selected away).
        const int src1 = 63 - __clzll(p1 | 1ull);
        const int src2 = 63 - __clzll(p2 | 1ull);
        const int top1 = 63 - __clzll(m1 | 1ull);
        const int top2 = 63 - __clzll(m2 | 1ull);

        const float f1 = __shfl(v1, src1);  // last dry in group-1 lanes < me
        const float g1 = __shfl(v1, top1);  // last dry in all of group 1
        const float f2 = __shfl(v2, src2);
        const float g2 = __shfl(v2, top2);

        const float fillA = m1 ? g1 : carry;       // state after first half
        const float seed1 = p1 ? f1 : carry;
        const float seed2 = p2 ? f2 : fillA;
        carry = m2 ? g2 : fillA;                   // state after this chunk

        f32x4 o;
        float run = seed1;
        if ((w1.x == 0) | first) run = a1.x;
        o.x = run;
        if (w1.y == 0) run = a1.y;
        o.y = run;
        if (w1.z == 0) run = a1.z;
        o.z = run;
        if (w1.w == 0) run = a1.w;
        o.w = run;
        __builtin_nontemporal_store(o, &Orow[base]);

        run = seed2;
        if (w2.x == 0) run = a2.x;
        o.x = run;
        if (w2.y == 0) run = a2.y;
        o.y = run;
        if (w2.z == 0) run = a2.z;
        o.z = run;
        if (w2.w == 0) run = a2.w;
        o.w = run;
        __builtin_nontemporal_store(o, &Orow[base + 64]);
    }
}

extern "C" void kernel_launch(void* const* d_in, const int* in_sizes, int n_in,
                              void* d_out, int out_size, void* d_ws, size_t ws_size,
                              hipStream_t stream) {
    const float* A = (const float*)d_in[0];
    const int* W = (const int*)d_in[1];
    float* O = (float*)d_out;

    const int B = in_sizes[0] / S_CONST;

    const int threads = 256;  // 4 waves per block
    const int blocks = (B * 64 + threads - 1) / threads;
    hipLaunchKernelGGL(ffill_kernel, dim3(blocks), dim3(threads), 0, stream,
                       A, W, O, B);
}

// Round 4
// 61.919 us; speedup vs baseline: 1.4134x; 1.0218x over previous
//
#include <hip/hip_runtime.h>

// Forward-fill per row. One 256-thread block (4 waves) per row; each wave
// owns a 2048-element segment = 4 chunks of 512 (2 coalesced f32x4/i32x4
// per lane per chunk). Phase 1: load all data to registers, ballot+clz
// per-chunk summaries, per-segment summary -> LDS. Barrier. Phase 2: seed
// from preceding segments, replay fill from registers, nontemporal store.

typedef float f32x4 __attribute__((ext_vector_type(4)));
typedef int i32x4 __attribute__((ext_vector_type(4)));

constexpr int S_CONST = 8192;
constexpr int NWAVE = 4;
constexpr int SEG = S_CONST / NWAVE;   // 2048
constexpr int NC = SEG / 512;          // 4 chunks per segment

__global__ __launch_bounds__(256) void ffill_kernel(const float* __restrict__ A,
                                                    const int* __restrict__ W,
                                                    float* __restrict__ O,
                                                    int B) {
    const int row = blockIdx.x;
    const int wid = threadIdx.x >> 6;
    const int lane = threadIdx.x & 63;

    __shared__ float s_val[NWAVE];
    __shared__ int s_has[NWAVE];

    const size_t seg_off = (size_t)row * (S_CONST / 4) + wid * (SEG / 4);
    const f32x4* __restrict__ Aseg = reinterpret_cast<const f32x4*>(A) + seg_off;
    const i32x4* __restrict__ Wseg = reinterpret_cast<const i32x4*>(W) + seg_off;
    f32x4* __restrict__ Oseg = reinterpret_cast<f32x4*>(O) + seg_off;

    const unsigned long long below = ((unsigned long long)1 << lane) - 1ull;

    // ---- Phase 1: load + summarize ----
    f32x4 a1[NC], a2[NC];
    float f1[NC], f2[NC], g1[NC], g2[NC];
    int dm[NC];                       // packed dry bits: grp1 bits0-3, grp2 bits4-7
    unsigned long long m1s[NC], m2s[NC];

    float segval = 0.0f;
    int seghas = 0;

    #pragma unroll
    for (int c = 0; c < NC; ++c) {
        const int base = c * 128 + lane;
        a1[c] = Aseg[base];
        a2[c] = Aseg[base + 64];
        const i32x4 w1 = Wseg[base];
        const i32x4 w2 = Wseg[base + 64];

        const bool first = (wid == 0) & (c == 0) & (lane == 0);  // global elem 0

        int d = 0;
        if ((w1.x == 0) | first) d |= 1;
        if (w1.y == 0) d |= 2;
        if (w1.z == 0) d |= 4;
        if (w1.w == 0) d |= 8;
        if (w2.x == 0) d |= 16;
        if (w2.y == 0) d |= 32;
        if (w2.z == 0) d |= 64;
        if (w2.w == 0) d |= 128;
        dm[c] = d;

        // per-lane last dry value within each 4-group
        float v1 = 0.f;
        if (d & 1) v1 = a1[c].x;
        if (d & 2) v1 = a1[c].y;
        if (d & 4) v1 = a1[c].z;
        if (d & 8) v1 = a1[c].w;
        float v2 = 0.f;
        if (d & 16) v2 = a2[c].x;
        if (d & 32) v2 = a2[c].y;
        if (d & 64) v2 = a2[c].z;
        if (d & 128) v2 = a2[c].w;

        const unsigned long long m1 = __ballot((d & 15) != 0);
        const unsigned long long m2 = __ballot((d >> 4) != 0);
        m1s[c] = m1;
        m2s[c] = m2;

        const unsigned long long p1 = m1 & below;
        const unsigned long long p2 = m2 & below;
        f1[c] = __shfl(v1, 63 - __clzll(p1 | 1ull));
        g1[c] = __shfl(v1, 63 - __clzll(m1 | 1ull));
        f2[c] = __shfl(v2, 63 - __clzll(p2 | 1ull));
        g2[c] = __shfl(v2, 63 - __clzll(m2 | 1ull));

        if (m1) segval = g1[c];
        if (m2) segval = g2[c];
        seghas |= (m1 | m2) != 0ull;
    }

    if (lane == 0) {
        s_val[wid] = segval;
        s_has[wid] = seghas;
    }
    __syncthreads();

    // seed = last dry value among preceding segments (wave 0 always has one)
    float seed = 0.0f;
    for (int j = wid - 1; j >= 0; --j) {
        if (s_has[j]) { seed = s_val[j]; break; }
    }

    // ---- Phase 2: replay fill from registers + store ----
    float carry = seed;
    #pragma unroll
    for (int c = 0; c < NC; ++c) {
        const int base = c * 128 + lane;
        const unsigned long long p1 = m1s[c] & below;
        const unsigned long long p2 = m2s[c] & below;

        const float fillA = (m1s[c] != 0ull) ? g1[c] : carry;
        const float seed1 = p1 ? f1[c] : carry;
        const float seed2 = p2 ? f2[c] : fillA;
        carry = (m2s[c] != 0ull) ? g2[c] : fillA;

        const int d = dm[c];
        f32x4 o;
        float run = seed1;
        if (d & 1) run = a1[c].x;
        o.x = run;
        if (d & 2) run = a1[c].y;
        o.y = run;
        if (d & 4) run = a1[c].z;
        o.z = run;
        if (d & 8) run = a1[c].w;
        o.w = run;
        __builtin_nontemporal_store(o, &Oseg[base]);

        run = seed2;
        if (d & 16) run = a2[c].x;
        o.x = run;
        if (d & 32) run = a2[c].y;
        o.y = run;
        if (d & 64) run = a2[c].z;
        o.z = run;
        if (d & 128) run = a2[c].w;
        o.w = run;
        __builtin_nontemporal_store(o, &Oseg[base + 64]);
    }
}

extern "C" void kernel_launch(void* const* d_in, const int* in_sizes, int n_in,
                              void* d_out, int out_size, void* d_ws, size_t ws_size,
                              hipStream_t stream) {
    const float* A = (const float*)d_in[0];
    const int* W = (const int*)d_in[1];
    float* O = (float*)d_out;

    const int B = in_sizes[0] / S_CONST;  // rows

    hipLaunchKernelGGL(ffill_kernel, dim3(B), dim3(256), 0, stream, A, W, O, B);
}